// Round 9
// baseline (2234.063 us; speedup 1.0000x reference)
//
#include <hip/hip_runtime.h>
#include <hip/hip_bf16.h>

typedef _Float16 half8 __attribute__((ext_vector_type(8)));
typedef _Float16 half4 __attribute__((ext_vector_type(4)));
typedef float    floatx4 __attribute__((ext_vector_type(4)));

#define B_TOT 4096
#define L_SEQ 2048
#define H_DIM 256
#define FUT   128
#define T_TOT (L_SEQ + FUT)   /* 2176 */
#define ROWS  16              /* batch rows per block, 256 blocks = 1/CU */

// tanh(p) = 1 - 2/(e^{2p}+1); exp2 over/underflow saturate to exact +-1.
__device__ __forceinline__ float tanh_fast(float p) {
    float e = __builtin_amdgcn_exp2f(p * 2.885390082f);     // e^(2p)
    return __builtin_fmaf(-2.0f, __builtin_amdgcn_rcpf(e + 1.0f), 1.0f);
}

// Barrier-free producer-consumer pipeline:
//  - a[kk] (h cols [32kk,32kk+32)) is produced by exactly wave kk -> 8
//    monotone step-flags in LDS replace __syncthreads.  Flag check at step s
//    waits for all flags >= s-1, which bounds wave drift to <=1 step; with
//    NBUF=3 h-buffers that makes all WAR hazards auto-satisfied.
//  - lin = 8-FMA register dot on each wave's own tanh outputs + shfl_xor
//    reduce + one ds_add_f32 per wave into the out-ring slot (replaces the
//    8-MFMA lin tile).  Future-phase feedback reads the summed slot, whose
//    completeness is guaranteed by the same flag check.
//  - x fetched per-wave (1 prefetched global load/step); out-ring flush
//    partitioned per-wave (each wave reads+stores+zeros its own 64 slots).
//  - fences: asm ""::"memory" after each spin; s_waitcnt lgkmcnt(0) before
//    each flag post (h-writes + atomicAdd complete before flag visible).
__global__ __launch_bounds__(512, 2) void rnn_seq_kernel(
    const float* __restrict__ x,      // [B, L]
    const float* __restrict__ W_ih,   // [H]
    const float* __restrict__ b_ih,   // [H]
    const float* __restrict__ W_hh,   // [H, H]
    const float* __restrict__ b_hh,   // [H]
    const float* __restrict__ W_lin,  // [H]
    const float* __restrict__ b_lin,  // [1]
    float* __restrict__ out)          // [B, T_TOT]
{
    __shared__ __align__(16) unsigned char hbuf[3][ROWS * 512]; // fp16, 3-buf
    __shared__ __align__(16) float obuf[64][17];                // out ring (t&63)
    __shared__ int flags[8];

    const int tid  = threadIdx.x;
    const int l    = tid & 63;
    const int w    = tid >> 6;       // wave 0..7
    const int ln15 = l & 15;
    const int lg   = l >> 4;         // 0..3
    const int b0   = blockIdx.x * ROWS;
    volatile int* vflags = flags;

    // ---- loop-invariant register state ----
    half8 wf[2][8];                   // W_hh A-frags: 2 N-tiles per wave
    #pragma unroll
    for (int i = 0; i < 2; ++i) {
        const int n = (2 * w + i) * 16 + ln15;
        #pragma unroll
        for (int kk = 0; kk < 8; ++kk) {
            const float* p = W_hh + n * H_DIM + kk * 32 + lg * 8;
            half8 v;
            #pragma unroll
            for (int j = 0; j < 8; ++j) v[j] = (_Float16)p[j];
            wf[i][kk] = v;
        }
    }
    floatx4 wih4[2], bia4[2];
    float wlp[2][4];                  // W_lin for this lane's own neurons
    #pragma unroll
    for (int i = 0; i < 2; ++i) {
        const int n0 = (2 * w + i) * 16 + lg * 4;
        #pragma unroll
        for (int r = 0; r < 4; ++r) {
            wih4[i][r] = W_ih[n0 + r];
            bia4[i][r] = b_ih[n0 + r] + b_hh[n0 + r];
            wlp[i][r]  = W_lin[n0 + r];
        }
    }
    const float blin = b_lin[0];

    // LDS byte offsets (XOR swizzle bits 4-6 keyed by row&7)
    int aoff[8];
    #pragma unroll
    for (int kk = 0; kk < 8; ++kk)
        aoff[kk] = (ln15 * 512 + kk * 64 + lg * 16) ^ ((ln15 & 7) << 4);
    int woff2[2];
    #pragma unroll
    for (int i = 0; i < 2; ++i)
        woff2[i] = (ln15 * 512 + (2 * w + i) * 32 + lg * 8) ^ ((ln15 & 7) << 4);

    // init: h0 = 0 in buf 0, obuf zeroed, flags = 0 ("step 0 written")
    *(floatx4*)(hbuf[0] + tid * 16) = floatx4{0.f, 0.f, 0.f, 0.f};
    #pragma unroll
    for (int i = 0; i < 3; ++i) {
        const int idx = i * 512 + tid;
        if (idx < 64 * 17) ((float*)obuf)[idx] = 0.f;
    }
    if (tid < 8) flags[tid] = 0;
    __syncthreads();

    float xm = x[(size_t)(b0 + ln15) * L_SEQ + 0];
    int rb = 0, wb = 1;

#define SPIN_WAIT(tgt)                                                        \
    do {                                                                      \
        int m_;                                                               \
        do {                                                                  \
            int f0 = vflags[0], f1 = vflags[1], f2 = vflags[2], f3 = vflags[3]; \
            int f4 = vflags[4], f5 = vflags[5], f6 = vflags[6], f7 = vflags[7]; \
            int a_ = f0 < f1 ? f0 : f1;  int b_ = f2 < f3 ? f2 : f3;          \
            int c_ = f4 < f5 ? f4 : f5;  int d_ = f6 < f7 ? f6 : f7;          \
            int e_ = a_ < b_ ? a_ : b_;  int g_ = c_ < d_ ? c_ : d_;          \
            m_ = e_ < g_ ? e_ : g_;                                           \
        } while (m_ < (tgt));                                                 \
        asm volatile("" ::: "memory");                                        \
    } while (0)

#define FLUSH_RING()                                                          \
    do {                                                                      \
        const int tb = s - 35;                                                \
        const int rr = tid >> 5, tt = tid & 31;                               \
        const int slot = (tb + tt) & 63;                                      \
        const float v_ = obuf[slot][rr];                                      \
        out[(size_t)(b0 + rr) * T_TOT + tb + tt] = v_ + blin;                 \
        obuf[slot][rr] = 0.f;                                                 \
    } while (0)

    // ============================ main phase ============================
    for (int s = 1; s <= L_SEQ; ++s) {
        SPIN_WAIT(s - 1);
        const unsigned char* hb = hbuf[rb];
        half8 a[8];
        #pragma unroll
        for (int kk = 0; kk < 8; ++kk)
            a[kk] = *(const half8*)(hb + aoff[kk]);
        float xnext = 0.0f;
        if (s < L_SEQ) xnext = x[(size_t)(b0 + ln15) * L_SEQ + s];

        // 2 chains per tile; chain0 init = fma(x, W_ih, bias)
        floatx4 acc[2][2];
        #pragma unroll
        for (int i = 0; i < 2; ++i) {
            #pragma unroll
            for (int r = 0; r < 4; ++r)
                acc[i][0][r] = __builtin_fmaf(xm, wih4[i][r], bia4[i][r]);
            acc[i][1] = floatx4{0, 0, 0, 0};
        }
        #pragma unroll
        for (int kk = 0; kk < 8; ++kk) {
            acc[0][kk & 1] = __builtin_amdgcn_mfma_f32_16x16x32_f16(wf[0][kk], a[kk], acc[0][kk & 1], 0, 0, 0);
            acc[1][kk & 1] = __builtin_amdgcn_mfma_f32_16x16x32_f16(wf[1][kk], a[kk], acc[1][kk & 1], 0, 0, 0);
        }
        // epilogue: tanh, h-write, lin partial
        unsigned char* hw = hbuf[wb];
        float tv[2][4];
        #pragma unroll
        for (int i = 0; i < 2; ++i) {
            const floatx4 av = acc[i][0] + acc[i][1];
            half4 hv;
            #pragma unroll
            for (int r = 0; r < 4; ++r) {
                tv[i][r] = tanh_fast(av[r]);
                hv[r] = (_Float16)tv[i][r];
            }
            *(half4*)(hw + woff2[i]) = hv;
        }
        float part = 0.f;
        #pragma unroll
        for (int i = 0; i < 2; ++i)
            #pragma unroll
            for (int r = 0; r < 4; ++r)
                part = __builtin_fmaf(tv[i][r], wlp[i][r], part);
        part += __shfl_xor(part, 16);
        part += __shfl_xor(part, 32);
        if (l < 16) atomicAdd(&obuf[(s - 1) & 63][l], part);

        asm volatile("s_waitcnt lgkmcnt(0)" ::: "memory");
        if (l == 0) vflags[w] = s;

        if (s >= 35 && (s & 31) == 3) FLUSH_RING();
        xm = xnext;
        rb = wb; wb = (wb == 2) ? 0 : wb + 1;
    }

    // ============================ future phase ============================
    for (int s = L_SEQ + 1; s <= T_TOT; ++s) {
        SPIN_WAIT(s - 1);
        const unsigned char* hb = hbuf[rb];
        half8 a[8];
        #pragma unroll
        for (int kk = 0; kk < 8; ++kk)
            a[kk] = *(const half8*)(hb + aoff[kk]);
        // feedback: completed lin sum for t = s-2 (covered by flag check)
        const float xf = obuf[(s - 2) & 63][ln15] + blin;

        floatx4 acc[2][2];
        #pragma unroll
        for (int i = 0; i < 2; ++i) {
            #pragma unroll
            for (int r = 0; r < 4; ++r)
                acc[i][0][r] = __builtin_fmaf(xf, wih4[i][r], bia4[i][r]);
            acc[i][1] = floatx4{0, 0, 0, 0};
        }
        #pragma unroll
        for (int kk = 0; kk < 8; ++kk) {
            acc[0][kk & 1] = __builtin_amdgcn_mfma_f32_16x16x32_f16(wf[0][kk], a[kk], acc[0][kk & 1], 0, 0, 0);
            acc[1][kk & 1] = __builtin_amdgcn_mfma_f32_16x16x32_f16(wf[1][kk], a[kk], acc[1][kk & 1], 0, 0, 0);
        }
        unsigned char* hw = hbuf[wb];
        float tv[2][4];
        #pragma unroll
        for (int i = 0; i < 2; ++i) {
            const floatx4 av = acc[i][0] + acc[i][1];
            half4 hv;
            #pragma unroll
            for (int r = 0; r < 4; ++r) {
                tv[i][r] = tanh_fast(av[r]);
                hv[r] = (_Float16)tv[i][r];
            }
            *(half4*)(hw + woff2[i]) = hv;
        }
        float part = 0.f;
        #pragma unroll
        for (int i = 0; i < 2; ++i)
            #pragma unroll
            for (int r = 0; r < 4; ++r)
                part = __builtin_fmaf(tv[i][r], wlp[i][r], part);
        part += __shfl_xor(part, 16);
        part += __shfl_xor(part, 32);
        if (l < 16) atomicAdd(&obuf[(s - 1) & 63][l], part);

        asm volatile("s_waitcnt lgkmcnt(0)" ::: "memory");
        if (l == 0) vflags[w] = s;

        if ((s & 31) == 3) FLUSH_RING();
        rb = wb; wb = (wb == 2) ? 0 : wb + 1;
    }

    __syncthreads();
    {   // final flush t = 2144..2175 (slots 32..63)
        const int rr = tid >> 5, tt = tid & 31;
        out[(size_t)(b0 + rr) * T_TOT + 2144 + tt] = obuf[32 + tt][rr] + blin;
    }
#undef SPIN_WAIT
#undef FLUSH_RING
}

extern "C" void kernel_launch(void* const* d_in, const int* in_sizes, int n_in,
                              void* d_out, int out_size, void* d_ws, size_t ws_size,
                              hipStream_t stream) {
    const float* x     = (const float*)d_in[0];
    const float* W_ih  = (const float*)d_in[1];
    const float* b_ih  = (const float*)d_in[2];
    const float* W_hh  = (const float*)d_in[3];
    const float* b_hh  = (const float*)d_in[4];
    const float* W_lin = (const float*)d_in[5];
    const float* b_lin = (const float*)d_in[6];
    float* out = (float*)d_out;
    rnn_seq_kernel<<<B_TOT / ROWS, 512, 0, stream>>>(x, W_ih, b_ih, W_hh, b_hh, W_lin, b_lin, out);
}